// Round 5
// baseline (34054.300 us; speedup 1.0000x reference)
//
#include <hip/hip_runtime.h>

#define B    64
#define T    512
#define H    600
#define G3   1800
#define IN0  300
#define NBLK 150    // blocks: each owns 4 j-values (150*4 = 600); <= 256 CUs -> co-resident
#define NTHR 256    // threads: (b=64) x (jj=4)
#define KPAD 1208   // LDS row stride (floats): 3*KPAD % 32 == 8 -> the 4 jj base
                    // addresses land on banks {0,8,16,24}; b128 reads cover 16
                    // disjoint banks, broadcast across lanes -> conflict-free.
// Static LDS = 12*1208*4 = 57,984 B (plain launch; cooperative launch silently
// rejected R2/R3 -- never again).

// ws layout (floats)
#define WC0_OFF 0
#define WC0_SZ  (900 * G3)
#define WC1_OFF (WC0_OFF + WC0_SZ)
#define WC1_SZ  (1200 * G3)
#define BC0_OFF (WC1_OFF + WC1_SZ)
#define BC1_OFF (BC0_OFF + H * 4)
#define HA_OFF  (BC1_OFF + H * 4)
#define HB_OFF  (HA_OFF + B * H)
#define BAR_OFF (HB_OFF + B * H + 64)

// ---- grid barriers: monotonic arrival counter, no reset (no reset/release
// ordering hazard; 1026 barriers * 150 blocks << 2^31).
// FAST: relaxed-only. No buffer_wbl2 / buffer_inv on the step path -- all
// cross-block step data (h) moves via agent-coherent bypass atomics instead.
__device__ __forceinline__ void bar_fast(int* cnt, int target) {
    __syncthreads();   // drains vmcnt -> all this block's h-stores are at IF$
    if (threadIdx.x == 0) {
        __hip_atomic_fetch_add(cnt, 1, __ATOMIC_RELAXED, __HIP_MEMORY_SCOPE_AGENT);
        while (__hip_atomic_load(cnt, __ATOMIC_RELAXED, __HIP_MEMORY_SCOPE_AGENT) < target)
            __builtin_amdgcn_s_sleep(2);
    }
    __syncthreads();
}
// HEAVY: acq_rel arrival (L2 writeback) + acquire spin (L2 invalidate).
// Used ONCE per call, at the L0->L1 boundary, to publish L0's cached ret writes.
__device__ __forceinline__ void bar_heavy(int* cnt, int target) {
    __syncthreads();
    if (threadIdx.x == 0) {
        __hip_atomic_fetch_add(cnt, 1, __ATOMIC_ACQ_REL, __HIP_MEMORY_SCOPE_AGENT);
        while (__hip_atomic_load(cnt, __ATOMIC_ACQUIRE, __HIP_MEMORY_SCOPE_AGENT) < target)
            __builtin_amdgcn_s_sleep(2);
    }
    __syncthreads();
}

__global__ void init_bar(int* bar) { bar[0] = 0; }

// Pack combined weights: WC[k][j*3+gate], k in [0, in_dim+H).
__global__ void build_wc(const float* __restrict__ Wih, const float* __restrict__ Whh,
                         float* __restrict__ WC, int in_dim, int ktot) {
    int idx = blockIdx.x * blockDim.x + threadIdx.x;
    if (idx >= ktot * G3) return;
    int k = idx / G3;
    int c = idx - k * G3;
    int j = c / 3;
    int g = c - j * 3;
    int grow = g * H + j;
    float v = (k < in_dim) ? Wih[grow * in_dim + k] : Whh[grow * H + (k - in_dim)];
    WC[idx] = v;
}

__global__ void build_bc(const float* __restrict__ bih0, const float* __restrict__ bhh0,
                         const float* __restrict__ bih1, const float* __restrict__ bhh1,
                         float* __restrict__ BC0, float* __restrict__ BC1) {
    int j = blockIdx.x * blockDim.x + threadIdx.x;
    if (j >= H) return;
    BC0[j * 4 + 0] = bih0[j] + bhh0[j];
    BC0[j * 4 + 1] = bih0[H + j] + bhh0[H + j];
    BC0[j * 4 + 2] = bih0[2 * H + j];
    BC0[j * 4 + 3] = bhh0[2 * H + j];
    BC1[j * 4 + 0] = bih1[j] + bhh1[j];
    BC1[j * 4 + 1] = bih1[H + j] + bhh1[H + j];
    BC1[j * 4 + 2] = bih1[2 * H + j];
    BC1[j * 4 + 3] = bhh1[2 * H + j];
}

// Triple fp32 dot over N4 float4s. a: CACHED global (x0 / ret rows -- read-only
// or boundary-published), double-buffered register pipeline. w: LDS b128
// broadcast. #pragma unroll 1 keeps ONE ping-pong copy (bounded VGPR).
template<int N4, int CH>
__device__ __forceinline__ void dot3f(const float4* __restrict__ ap,
                                      const float* __restrict__ wr,
                                      const float* __restrict__ wz,
                                      const float* __restrict__ wn,
                                      float& sr, float& sz, float& sn) {
    constexpr int NCH = N4 / CH;
    static_assert(N4 % CH == 0, "chunking");
    float4 A[CH], Bf[CH];
    #pragma unroll
    for (int i = 0; i < CH; ++i) A[i] = ap[i];
    #pragma unroll 1
    for (int c = 0; c < NCH; c += 2) {
        if (c + 1 < NCH) {
            const float4* p = ap + (c + 1) * CH;
            #pragma unroll
            for (int i = 0; i < CH; ++i) Bf[i] = p[i];
        }
        #pragma unroll
        for (int i = 0; i < CH; ++i) {
            const int k = (c * CH + i) * 4;
            float4 a = A[i];
            const float4 wR = *(const float4*)(wr + k);
            const float4 wZ = *(const float4*)(wz + k);
            const float4 wN = *(const float4*)(wn + k);
            sr += a.x * wR.x + a.y * wR.y + a.z * wR.z + a.w * wR.w;
            sz += a.x * wZ.x + a.y * wZ.y + a.z * wZ.z + a.w * wZ.w;
            sn += a.x * wN.x + a.y * wN.y + a.z * wN.z + a.w * wN.w;
        }
        if (c + 1 < NCH) {
            if (c + 2 < NCH) {
                const float4* p = ap + (c + 2) * CH;
                #pragma unroll
                for (int i = 0; i < CH; ++i) A[i] = p[i];
            }
            #pragma unroll
            for (int i = 0; i < CH; ++i) {
                const int k = ((c + 1) * CH + i) * 4;
                float4 a = Bf[i];
                const float4 wR = *(const float4*)(wr + k);
                const float4 wZ = *(const float4*)(wz + k);
                const float4 wN = *(const float4*)(wn + k);
                sr += a.x * wR.x + a.y * wR.y + a.z * wR.z + a.w * wR.w;
                sz += a.x * wZ.x + a.y * wZ.y + a.z * wZ.z + a.w * wZ.w;
                sn += a.x * wN.x + a.y * wN.y + a.z * wN.z + a.w * wN.w;
            }
        }
    }
}

// Triple dot over the h row: NU u64 agent-coherent bypass loads
// (global_load_dwordx2 sc0 sc1 -- reads the IF$ coherence point, no cache
// maintenance needed). Ping-pong keeps CH loads in flight; relaxed atomics get
// precise per-register vmcnt waits from the compiler, not serialization.
template<int NU, int CH>
__device__ __forceinline__ void dot3h(const unsigned long long* hp,
                                      const float* __restrict__ wr,
                                      const float* __restrict__ wz,
                                      const float* __restrict__ wn,
                                      float& sr, float& sz, float& sn) {
    constexpr int NCH = NU / CH;
    static_assert(NU % CH == 0 && CH % 2 == 0 && NCH % 2 == 0, "chunking");
    unsigned long long A[CH], Bu[CH];
    #pragma unroll
    for (int i = 0; i < CH; ++i)
        A[i] = __hip_atomic_load(hp + i, __ATOMIC_RELAXED, __HIP_MEMORY_SCOPE_AGENT);
    #pragma unroll 1
    for (int c = 0; c < NCH; c += 2) {
        {   // prefetch chunk c+1
            const unsigned long long* p = hp + (c + 1) * CH;
            #pragma unroll
            for (int i = 0; i < CH; ++i)
                Bu[i] = __hip_atomic_load(p + i, __ATOMIC_RELAXED, __HIP_MEMORY_SCOPE_AGENT);
        }
        #pragma unroll
        for (int i = 0; i < CH; i += 2) {
            const int k = (c * CH + i) * 2;
            float2 a0 = __builtin_bit_cast(float2, A[i]);
            float2 a1 = __builtin_bit_cast(float2, A[i + 1]);
            const float4 wR = *(const float4*)(wr + k);
            const float4 wZ = *(const float4*)(wz + k);
            const float4 wN = *(const float4*)(wn + k);
            sr += a0.x * wR.x + a0.y * wR.y + a1.x * wR.z + a1.y * wR.w;
            sz += a0.x * wZ.x + a0.y * wZ.y + a1.x * wZ.z + a1.y * wZ.w;
            sn += a0.x * wN.x + a0.y * wN.y + a1.x * wN.z + a1.y * wN.w;
        }
        {
            if (c + 2 < NCH) {   // prefetch chunk c+2
                const unsigned long long* p = hp + (c + 2) * CH;
                #pragma unroll
                for (int i = 0; i < CH; ++i)
                    A[i] = __hip_atomic_load(p + i, __ATOMIC_RELAXED, __HIP_MEMORY_SCOPE_AGENT);
            }
            #pragma unroll
            for (int i = 0; i < CH; i += 2) {
                const int k = ((c + 1) * CH + i) * 2;
                float2 a0 = __builtin_bit_cast(float2, Bu[i]);
                float2 a1 = __builtin_bit_cast(float2, Bu[i + 1]);
                const float4 wR = *(const float4*)(wr + k);
                const float4 wZ = *(const float4*)(wz + k);
                const float4 wN = *(const float4*)(wn + k);
                sr += a0.x * wR.x + a0.y * wR.y + a1.x * wR.z + a1.y * wR.w;
                sz += a0.x * wZ.x + a0.y * wZ.y + a1.x * wZ.z + a1.y * wZ.w;
                sn += a0.x * wN.x + a0.y * wN.y + a1.x * wN.z + a1.y * wN.w;
            }
        }
    }
}

template<int LAYER>
__device__ void gru_layer(const float* xsrc, const float* __restrict__ hid,
                          const float* __restrict__ WC, const float* __restrict__ BC,
                          float* __restrict__ hA, float* __restrict__ hB,
                          float* ret, float* __restrict__ outh,
                          float* Wl, int* cnt, int& btgt) {
    constexpr int IN_DIM = LAYER ? H : IN0;
    constexpr int K = IN_DIM + H;
    const int tid = threadIdx.x;
    const int bb = tid >> 2;
    const int jj = tid & 3;
    const int j = blockIdx.x * 4 + jj;
    const int wcol0 = blockIdx.x * 12;

    // Load this block's 12 W columns into LDS once per layer (cached reads).
    for (int idx = tid; idx < 12 * K; idx += NTHR) {
        int k = idx / 12;
        int c = idx - k * 12;
        Wl[c * KPAD + k] = WC[(size_t)k * G3 + wcol0 + c];
    }
    {   // init h via BYPASS stores so bypass readers see it (grid covers B*H)
        int g = blockIdx.x * NTHR + tid;
        __hip_atomic_store(&hA[g], hid[g], __ATOMIC_RELAXED, __HIP_MEMORY_SCOPE_AGENT);
    }
    // L0: fast barrier. L0->L1 boundary: HEAVY (publishes L0's cached ret
    // writes; L1 then reads ret with normal cached loads).
    if (LAYER == 0) bar_fast(cnt, btgt); else bar_heavy(cnt, btgt);
    btgt += NBLK;

    float* hc = hA;
    float* hn = hB;
    const float bx  = BC[j * 4 + 0];
    const float by  = BC[j * 4 + 1];
    const float bgn = BC[j * 4 + 2];
    const float bhn = BC[j * 4 + 3];
    const float* wr = &Wl[(jj * 3 + 0) * KPAD];
    const float* wz = &Wl[(jj * 3 + 1) * KPAD];
    const float* wn = &Wl[(jj * 3 + 2) * KPAD];
    float hold = 0.0f;
    float hnv = 0.0f;

    for (int t = 0; t < T; ++t) {
        float sr = 0.f, sz = 0.f, sgn = 0.f, shn = 0.f;
        dot3f<IN_DIM / 4, 15>((const float4*)(xsrc + ((size_t)bb * T + t) * IN_DIM),
                              wr, wz, wn, sr, sz, sgn);
        dot3h<H / 2, 30>((const unsigned long long*)(hc + bb * H),
                         wr + IN_DIM, wz + IN_DIM, wn + IN_DIM, sr, sz, shn);
        float r = 1.f / (1.f + __expf(-(sr + bx)));
        float z = 1.f / (1.f + __expf(-(sz + by)));
        float n = tanhf(sgn + bgn + r * (shn + bhn));
        float hv = __hip_atomic_load(&hc[bb * H + j], __ATOMIC_RELAXED, __HIP_MEMORY_SCOPE_AGENT);
        hnv = (1.f - z) * n + z * hv;
        __hip_atomic_store(&hn[bb * H + j], hnv, __ATOMIC_RELAXED, __HIP_MEMORY_SCOPE_AGENT);
        if (LAYER == 0) {
            ret[((size_t)bb * T + t) * H + j] = hnv;       // cached; published at boundary
        } else {
            if (t > 0) ret[((size_t)bb * T + (t - 1)) * H + j] = hold;  // lag-write, cached
            hold = hnv;
        }
        bar_fast(cnt, btgt);
        btgt += NBLK;
        float* tmp = hc; hc = hn; hn = tmp;
    }
    if (LAYER == 1) {
        ret[((size_t)bb * T + (T - 1)) * H + j] = hold;
    }
    outh[bb * H + j] = hnv;   // cached; kernel-end flush publishes to host
}

__global__ void __launch_bounds__(NTHR, 1) gru_main(
    const float* x0, const float* __restrict__ hid,
    const float* __restrict__ WC0, const float* __restrict__ WC1,
    const float* __restrict__ BC0, const float* __restrict__ BC1,
    float* __restrict__ hA, float* __restrict__ hB,
    float* ret, float* __restrict__ outh, int* bar) {
    __shared__ __align__(16) float Wl[12 * KPAD];   // 57,984 B
    int btgt = NBLK;
    gru_layer<0>(x0, hid,          WC0, BC0, hA, hB, ret, outh,         Wl, bar, btgt);
    gru_layer<1>(ret, hid + B * H, WC1, BC1, hA, hB, ret, outh + B * H, Wl, bar, btgt);
}

extern "C" void kernel_launch(void* const* d_in, const int* in_sizes, int n_in,
                              void* d_out, int out_size, void* d_ws, size_t ws_size,
                              hipStream_t stream) {
    const float* x0   = (const float*)d_in[0];
    const float* hid  = (const float*)d_in[1];
    const float* Wih0 = (const float*)d_in[2];
    const float* Whh0 = (const float*)d_in[3];
    const float* bih0 = (const float*)d_in[4];
    const float* bhh0 = (const float*)d_in[5];
    const float* Wih1 = (const float*)d_in[6];
    const float* Whh1 = (const float*)d_in[7];
    const float* bih1 = (const float*)d_in[8];
    const float* bhh1 = (const float*)d_in[9];

    float* ws  = (float*)d_ws;
    float* WC0 = ws + WC0_OFF;
    float* WC1 = ws + WC1_OFF;
    float* BC0 = ws + BC0_OFF;
    float* BC1 = ws + BC1_OFF;
    float* hA  = ws + HA_OFF;
    float* hB  = ws + HB_OFF;
    int*   bar = (int*)(ws + BAR_OFF);

    float* ret  = (float*)d_out;
    float* outh = ret + (size_t)B * T * H;

    {
        int n0 = 900 * G3;
        build_wc<<<(n0 + 255) / 256, 256, 0, stream>>>(Wih0, Whh0, WC0, IN0, 900);
        int n1 = 1200 * G3;
        build_wc<<<(n1 + 255) / 256, 256, 0, stream>>>(Wih1, Whh1, WC1, H, 1200);
        build_bc<<<(H + 255) / 256, 256, 0, stream>>>(bih0, bhh0, bih1, bhh1, BC0, BC1);
        init_bar<<<1, 1, 0, stream>>>(bar);
    }

    gru_main<<<dim3(NBLK), dim3(NTHR), 0, stream>>>(
        x0, hid, WC0, WC1, BC0, BC1, hA, hB, ret, outh, bar);
}